// Round 1
// baseline (348.975 us; speedup 1.0000x reference)
//
#include <hip/hip_runtime.h>
#include <math.h>

#define B_  2
#define Q_  2048
#define CQ_ 512
#define H_  8
#define D_  64
#define M_  (B_*Q_)   // 4096

typedef __bf16 bf16;
typedef __bf16 bf16x8 __attribute__((ext_vector_type(8)));
typedef float  f32x4  __attribute__((ext_vector_type(4)));

// ---------------------------------------------------------------------------
// fp32 GEMM:  C[M,N] = A[M,512] * W[N,512]^T   (W row-major [N][512])
// BM=128 rows, BN in {64,128}. 256 threads; thread = 8 x (BN/16) microtile.
// EPI 0: qkv epilogue -> scatter q(scaled,bf16)/k(bf16) to [B,H,Q,D], v to [B,H,D,Q]
// EPI 1: gate epilogue -> sigmoid(c + bvec) -> fout [M,512] fp32
// EPI 2: out  epilogue -> c + bvec -> fout [M,512] fp32
// ---------------------------------------------------------------------------
template<int BN, int EPI>
__global__ __launch_bounds__(256)
void gemm_f32(const float* __restrict__ A, const float* __restrict__ W,
              const float* __restrict__ bvec, float* __restrict__ fout,
              bf16* __restrict__ qb, bf16* __restrict__ kb, bf16* __restrict__ vb)
{
    constexpr int NG = BN / 64;                 // column groups of 64
    __shared__ float As[16][132];               // [k][m], padded
    __shared__ float Bs[16][BN + 4];            // [k][n], padded

    const int tid = threadIdx.x;
    const int tx = tid & 15, ty = tid >> 4;
    const int bm = blockIdx.x * 128;
    const int bn = blockIdx.y * BN;

    float acc[8][NG * 4];
    #pragma unroll
    for (int i = 0; i < 8; ++i)
        #pragma unroll
        for (int j = 0; j < NG * 4; ++j) acc[i][j] = 0.f;

    for (int k0 = 0; k0 < 512; k0 += 16) {
        // stage A tile 128x16 (transpose into [k][m])
        {
            const int r = tid >> 1, kk = (tid & 1) * 8;
            const float4 a0 = *(const float4*)(A + (size_t)(bm + r) * 512 + k0 + kk);
            const float4 a1 = *(const float4*)(A + (size_t)(bm + r) * 512 + k0 + kk + 4);
            As[kk + 0][r] = a0.x; As[kk + 1][r] = a0.y; As[kk + 2][r] = a0.z; As[kk + 3][r] = a0.w;
            As[kk + 4][r] = a1.x; As[kk + 5][r] = a1.y; As[kk + 6][r] = a1.z; As[kk + 7][r] = a1.w;
        }
        if constexpr (BN == 128) {
            const int r = tid >> 1, kk = (tid & 1) * 8;
            const float4 b0 = *(const float4*)(W + (size_t)(bn + r) * 512 + k0 + kk);
            const float4 b1 = *(const float4*)(W + (size_t)(bn + r) * 512 + k0 + kk + 4);
            Bs[kk + 0][r] = b0.x; Bs[kk + 1][r] = b0.y; Bs[kk + 2][r] = b0.z; Bs[kk + 3][r] = b0.w;
            Bs[kk + 4][r] = b1.x; Bs[kk + 5][r] = b1.y; Bs[kk + 6][r] = b1.z; Bs[kk + 7][r] = b1.w;
        } else {
            const int r = tid >> 2, kk = (tid & 3) * 4;
            const float4 b0 = *(const float4*)(W + (size_t)(bn + r) * 512 + k0 + kk);
            Bs[kk + 0][r] = b0.x; Bs[kk + 1][r] = b0.y; Bs[kk + 2][r] = b0.z; Bs[kk + 3][r] = b0.w;
        }
        __syncthreads();
        #pragma unroll
        for (int k = 0; k < 16; ++k) {
            float ar[8];
            *(float4*)&ar[0] = *(const float4*)&As[k][ty * 8];
            *(float4*)&ar[4] = *(const float4*)&As[k][ty * 8 + 4];
            float br[NG * 4];
            #pragma unroll
            for (int jg = 0; jg < NG; ++jg)
                *(float4*)&br[jg * 4] = *(const float4*)&Bs[k][jg * 64 + tx * 4];
            #pragma unroll
            for (int i = 0; i < 8; ++i)
                #pragma unroll
                for (int j = 0; j < NG * 4; ++j)
                    acc[i][j] += ar[i] * br[j];
        }
        __syncthreads();
    }

    #pragma unroll
    for (int i = 0; i < 8; ++i) {
        const int m = bm + ty * 8 + i;
        const int b = m >> 11, qq = m & 2047;
        #pragma unroll
        for (int jg = 0; jg < NG; ++jg) {
            #pragma unroll
            for (int jj = 0; jj < 4; ++jj) {
                const int n = bn + jg * 64 + tx * 4 + jj;
                const float c = acc[i][jg * 4 + jj];
                if constexpr (EPI == 0) {
                    const int part = n >> 9, e5 = n & 511;
                    const int h = e5 >> 6, d = e5 & 63;
                    if (part == 0)
                        qb[(((size_t)(b * H_ + h)) * Q_ + qq) * D_ + d] = (bf16)(c * 0.125f);
                    else if (part == 1)
                        kb[(((size_t)(b * H_ + h)) * Q_ + qq) * D_ + d] = (bf16)c;
                    else
                        vb[(((size_t)(b * H_ + h)) * D_ + d) * Q_ + qq] = (bf16)c;
                } else if constexpr (EPI == 1) {
                    const float x = c + bvec[n];
                    fout[(size_t)m * 512 + n] = 1.f / (1.f + __expf(-x));
                } else {
                    fout[(size_t)m * 512 + n] = c + bvec[n];
                }
            }
        }
    }
}

// ---------------------------------------------------------------------------
// MFMA flash attention. Block = 256 threads = 4 waves; block covers 64 queries
// of one (b,h); each wave owns 16 query rows. Iterates 32 key tiles of 64.
// q/k in [B,H,Q,D] bf16 (q pre-scaled by 1/8), v transposed [B,H,D,Q] bf16.
// Epilogue: o = (acc/l) * gate, written fp32 to og [B*Q, 512].
// ---------------------------------------------------------------------------
__global__ __launch_bounds__(256)
void attn_kernel(const bf16* __restrict__ qb, const bf16* __restrict__ kb,
                 const bf16* __restrict__ vb, const float* __restrict__ bias,
                 const float* __restrict__ g, float* __restrict__ og)
{
    __shared__ __align__(16) bf16 Ks[64 * 80];      // [key][d]   pad 80
    __shared__ __align__(16) bf16 Vs[64 * 80];      // [d][key]   pad 80
    __shared__ __align__(16) bf16 Ps[4][16 * 80];   // per-wave [qrow][key]

    const int tid  = threadIdx.x;
    const int wv   = tid >> 6, lane = tid & 63;
    const int l15  = lane & 15, quad = lane >> 4;
    const int bh   = blockIdx.y;             // b*H + h
    const int b    = bh >> 3, h = bh & 7;
    const int q0   = blockIdx.x * 64;
    const int qrow = q0 + wv * 16;           // wave's first query row

    // Q fragments (A-operand layout), loaded once from global
    const bf16* qptr = qb + ((size_t)bh * Q_ + qrow + l15) * D_;
    const bf16x8 aq0 = *(const bf16x8*)(qptr + quad * 8);
    const bf16x8 aq1 = *(const bf16x8*)(qptr + 32 + quad * 8);

    f32x4 acc_o[4] = {};                     // C-layout: row=quad*4+reg, col=dt*16+l15
    float mrow[4] = {-INFINITY, -INFINITY, -INFINITY, -INFINITY};
    float lrow[4] = {0.f, 0.f, 0.f, 0.f};

    const bf16*  kbase = kb + (size_t)bh * Q_ * D_;
    const bf16*  vbase = vb + (size_t)bh * D_ * Q_;
    const float* brow  = bias + (size_t)b * Q_ * Q_;

    for (int k0 = 0; k0 < Q_; k0 += 64) {
        __syncthreads();
        // stage K (contiguous 8 KB slab) and V (64 rows of 128 B) into LDS
        #pragma unroll
        for (int p = 0; p < 2; ++p) {
            const int elem = p * 2048 + tid * 8;
            const int rr = elem >> 6, cc = elem & 63;
            *(float4*)(Ks + rr * 80 + cc) =
                *(const float4*)(kbase + (size_t)k0 * 64 + elem);
            *(float4*)(Vs + rr * 80 + cc) =
                *(const float4*)(vbase + (size_t)rr * Q_ + k0 + cc);
        }
        __syncthreads();

        // ---- scores: 16q x 64k via 4 MFMA pairs; C-layout + bias ----
        float sc[4][4];                      // [kt][reg]
        #pragma unroll
        for (int kt = 0; kt < 4; ++kt) {
            f32x4 sacc = {0.f, 0.f, 0.f, 0.f};
            const bf16* kp = Ks + (kt * 16 + l15) * 80 + quad * 8;
            const bf16x8 bk0 = *(const bf16x8*)(kp);
            const bf16x8 bk1 = *(const bf16x8*)(kp + 32);
            sacc = __builtin_amdgcn_mfma_f32_16x16x32_bf16(aq0, bk0, sacc, 0, 0, 0);
            sacc = __builtin_amdgcn_mfma_f32_16x16x32_bf16(aq1, bk1, sacc, 0, 0, 0);
            const float* bp = brow + (size_t)(qrow + quad * 4) * Q_ + k0 + kt * 16 + l15;
            #pragma unroll
            for (int r = 0; r < 4; ++r) sc[kt][r] = sacc[r] + bp[(size_t)r * Q_];
        }

        // ---- online softmax (row = quad*4+reg, spread over 16 lanes) ----
        float tmax[4];
        #pragma unroll
        for (int r = 0; r < 4; ++r)
            tmax[r] = fmaxf(fmaxf(sc[0][r], sc[1][r]), fmaxf(sc[2][r], sc[3][r]));
        #pragma unroll
        for (int off = 1; off < 16; off <<= 1)
            #pragma unroll
            for (int r = 0; r < 4; ++r)
                tmax[r] = fmaxf(tmax[r], __shfl_xor(tmax[r], off, 64));

        float alpha[4];
        #pragma unroll
        for (int r = 0; r < 4; ++r) {
            const float mn = fmaxf(mrow[r], tmax[r]);
            alpha[r] = __expf(mrow[r] - mn);       // exp(-inf)=0 on first tile
            mrow[r] = mn;
        }
        float rsum[4];
        #pragma unroll
        for (int r = 0; r < 4; ++r) {
            #pragma unroll
            for (int kt = 0; kt < 4; ++kt) sc[kt][r] = __expf(sc[kt][r] - mrow[r]);
            rsum[r] = sc[0][r] + sc[1][r] + sc[2][r] + sc[3][r];
        }
        #pragma unroll
        for (int off = 1; off < 16; off <<= 1)
            #pragma unroll
            for (int r = 0; r < 4; ++r)
                rsum[r] += __shfl_xor(rsum[r], off, 64);
        #pragma unroll
        for (int r = 0; r < 4; ++r) lrow[r] = lrow[r] * alpha[r] + rsum[r];
        #pragma unroll
        for (int dt = 0; dt < 4; ++dt)
            #pragma unroll
            for (int r = 0; r < 4; ++r) acc_o[dt][r] *= alpha[r];

        // ---- P: C-layout -> A-layout via per-wave LDS transpose ----
        bf16* pw = Ps[wv];
        #pragma unroll
        for (int kt = 0; kt < 4; ++kt)
            #pragma unroll
            for (int r = 0; r < 4; ++r)
                pw[(quad * 4 + r) * 80 + kt * 16 + l15] = (bf16)sc[kt][r];
        __asm__ volatile("s_waitcnt lgkmcnt(0)" ::: "memory");

        // ---- PV: acc_o += P[16x64] * V[64x64] ----
        #pragma unroll
        for (int kt2 = 0; kt2 < 2; ++kt2) {
            const bf16x8 ap = *(const bf16x8*)(pw + l15 * 80 + kt2 * 32 + quad * 8);
            #pragma unroll
            for (int dt = 0; dt < 4; ++dt) {
                const bf16x8 bv = *(const bf16x8*)(Vs + (dt * 16 + l15) * 80 + kt2 * 32 + quad * 8);
                acc_o[dt] = __builtin_amdgcn_mfma_f32_16x16x32_bf16(ap, bv, acc_o[dt], 0, 0, 0);
            }
        }
    }

    // ---- normalize, gate, store fp32 to og [B*Q, 512] ----
    #pragma unroll
    for (int r = 0; r < 4; ++r) {
        const float inv = 1.f / lrow[r];
        const int qg = qrow + quad * 4 + r;
        const size_t rowoff = ((size_t)(b * Q_ + qg)) * 512 + h * 64;
        #pragma unroll
        for (int dt = 0; dt < 4; ++dt) {
            const int col = dt * 16 + l15;
            og[rowoff + col] = acc_o[dt][r] * inv * g[rowoff + col];
        }
    }
}

// ---------------------------------------------------------------------------
extern "C" void kernel_launch(void* const* d_in, const int* in_sizes, int n_in,
                              void* d_out, int out_size, void* d_ws, size_t ws_size,
                              hipStream_t stream)
{
    const float* q_x   = (const float*)d_in[0];
    // d_in[1] = kv_x, unused by the reference
    const float* bias  = (const float*)d_in[2];
    const float* w_qkv = (const float*)d_in[3];
    const float* w_o   = (const float*)d_in[4];
    const float* b_o   = (const float*)d_in[5];
    const float* w_g   = (const float*)d_in[6];
    const float* b_g   = (const float*)d_in[7];
    float* out = (float*)d_out;

    char* ws = (char*)d_ws;
    bf16*  qb  = (bf16*)(ws);                          // 4 MB  [B,H,Q,D]
    bf16*  kb  = (bf16*)(ws + (4u << 20));             // 4 MB  [B,H,Q,D]
    bf16*  vb  = (bf16*)(ws + (8u << 20));             // 4 MB  [B,H,D,Q]
    float* gbuf= (float*)(ws + (12u << 20));           // 8 MB  [B*Q,512]
    float* og  = (float*)(ws + (20u << 20));           // 8 MB  [B*Q,512]

    // 1) fused QKV projection (fp32), scatter to bf16 q/k/v layouts
    gemm_f32<128, 0><<<dim3(32, 12), 256, 0, stream>>>(q_x, w_qkv, nullptr, nullptr, qb, kb, vb);
    // 2) gate projection + sigmoid (fp32)
    gemm_f32<64, 1><<<dim3(32, 8), 256, 0, stream>>>(q_x, w_g, b_g, gbuf, nullptr, nullptr, nullptr);
    // 3) MFMA flash attention + gating
    attn_kernel<<<dim3(Q_ / 64, B_ * H_), 256, 0, stream>>>(qb, kb, vb, bias, gbuf, og);
    // 4) output projection + b_o (fp32)
    gemm_f32<64, 2><<<dim3(32, 8), 256, 0, stream>>>(og, w_o, b_o, out, nullptr, nullptr, nullptr);
}

// Round 2
// 204.195 us; speedup vs baseline: 1.7090x; 1.7090x over previous
//
#include <hip/hip_runtime.h>
#include <math.h>

#define B_  2
#define Q_  2048
#define CQ_ 512
#define H_  8
#define D_  64
#define M_  (B_*Q_)   // 4096

typedef __bf16 bf16;
typedef __bf16 bf16x8 __attribute__((ext_vector_type(8)));
typedef float  f32x4  __attribute__((ext_vector_type(4)));

// async global->LDS, 16 bytes per lane; lds dest = wave-uniform base + lane*16
__device__ __forceinline__ void gl_lds16(const bf16* g, bf16* l) {
    __builtin_amdgcn_global_load_lds(
        (const __attribute__((address_space(1))) unsigned int*)g,
        (__attribute__((address_space(3))) unsigned int*)l, 16, 0, 0);
}

// ---------------------------------------------------------------------------
// fp32 -> bf16 conversion: q_x -> qxb, w_qkv+w_g -> wcat (concat rows), w_o -> wob
// ---------------------------------------------------------------------------
#define S0 (4096*512)    // q_x
#define S1 (1536*512)    // w_qkv
#define S2 (512*512)     // w_g
#define S3 (512*512)     // w_o
__global__ __launch_bounds__(256)
void convert_kernel(const float* __restrict__ qx, const float* __restrict__ wqkv,
                    const float* __restrict__ wg, const float* __restrict__ wo,
                    bf16* __restrict__ qxb, bf16* __restrict__ wcat, bf16* __restrict__ wob)
{
    const long long t = (long long)blockIdx.x * 256 + threadIdx.x;
    const long long e = t * 8;
    const float* src; bf16* dst;
    if (e < S0)                { src = qx + e;                  dst = qxb + e; }
    else if (e < S0 + S1)      { src = wqkv + (e - S0);         dst = wcat + (e - S0); }
    else if (e < S0 + S1 + S2) { src = wg + (e - S0 - S1);      dst = wcat + S1 + (e - S0 - S1); }
    else                       { src = wo + (e - S0 - S1 - S2); dst = wob + (e - S0 - S1 - S2); }
    const float4 a = *(const float4*)(src);
    const float4 b = *(const float4*)(src + 4);
    bf16x8 v;
    v[0] = (bf16)a.x; v[1] = (bf16)a.y; v[2] = (bf16)a.z; v[3] = (bf16)a.w;
    v[4] = (bf16)b.x; v[5] = (bf16)b.y; v[6] = (bf16)b.z; v[7] = (bf16)b.w;
    *(bf16x8*)dst = v;
}

// ---------------------------------------------------------------------------
// bf16 MFMA GEMM: C[M,N] = A[M,512] * W[N,512]^T, K=512, BK=32.
// Block 256 = 4 waves in 2x2; wave tile (BM/2)x(BN/2); 16x16x32 MFMA.
// EPI 0: n<512 -> q (scaled, bf16 [B,H,Q,D]); <1024 -> k; <1536 -> v ([B,H,D,Q]);
//        else gate: sigmoid(c + b_g) -> gb bf16 [M,512]
// EPI 1: out[m*512+n] = c + b_o[n]  (fp32)
// ---------------------------------------------------------------------------
template<int BM, int BN, int EPI>
__global__ __launch_bounds__(256)
void gemm_bf16(const bf16* __restrict__ A, const bf16* __restrict__ W,
               const float* __restrict__ bvec, float* __restrict__ fout,
               bf16* __restrict__ qb, bf16* __restrict__ kb, bf16* __restrict__ vb,
               bf16* __restrict__ gb)
{
    constexpr int MI = BM / 32, NJ = BN / 32;
    __shared__ __align__(16) bf16 As[BM * 32];
    __shared__ __align__(16) bf16 Bs[BN * 32];

    const int t = threadIdx.x;
    const int w = t >> 6, lane = t & 63;
    const int l15 = lane & 15, quad = lane >> 4;
    const int wm = w & 1, wn = w >> 1;
    const int bm = blockIdx.x * BM;
    const int bn = blockIdx.y * BN;

    f32x4 acc[MI][NJ] = {};

    const int rr = t >> 2;              // staging row within 64-row slab
    const int cc = (t & 3) * 8;         // staging k-offset (elements)

    for (int k0 = 0; k0 < 512; k0 += 32) {
        #pragma unroll
        for (int i = 0; i < BM / 64; ++i)
            gl_lds16(A + (size_t)(bm + i * 64 + rr) * 512 + k0 + cc,
                     As + (i * 64 + w * 16) * 32);
        #pragma unroll
        for (int i = 0; i < BN / 64; ++i)
            gl_lds16(W + (size_t)(bn + i * 64 + rr) * 512 + k0 + cc,
                     Bs + (i * 64 + w * 16) * 32);
        __asm__ volatile("s_waitcnt vmcnt(0)" ::: "memory");
        __syncthreads();

        bf16x8 af[MI], bfr[NJ];
        #pragma unroll
        for (int i = 0; i < MI; ++i)
            af[i] = *(const bf16x8*)(As + (wm * (BM / 2) + i * 16 + l15) * 32 + quad * 8);
        #pragma unroll
        for (int j = 0; j < NJ; ++j)
            bfr[j] = *(const bf16x8*)(Bs + (wn * (BN / 2) + j * 16 + l15) * 32 + quad * 8);
        #pragma unroll
        for (int i = 0; i < MI; ++i)
            #pragma unroll
            for (int j = 0; j < NJ; ++j)
                acc[i][j] = __builtin_amdgcn_mfma_f32_16x16x32_bf16(af[i], bfr[j], acc[i][j], 0, 0, 0);
        __syncthreads();
    }

    #pragma unroll
    for (int i = 0; i < MI; ++i) {
        #pragma unroll
        for (int r = 0; r < 4; ++r) {
            const int m = bm + wm * (BM / 2) + i * 16 + quad * 4 + r;
            const int b = m >> 11, qq = m & 2047;
            #pragma unroll
            for (int j = 0; j < NJ; ++j) {
                const int n = bn + wn * (BN / 2) + j * 16 + l15;
                const float c = acc[i][j][r];
                if constexpr (EPI == 0) {
                    const int part = n >> 9;
                    const int h = (n >> 6) & 7, d = n & 63;
                    if (part == 0)
                        qb[(((size_t)(b * H_ + h)) * Q_ + qq) * D_ + d] = (bf16)(c * 0.125f);
                    else if (part == 1)
                        kb[(((size_t)(b * H_ + h)) * Q_ + qq) * D_ + d] = (bf16)c;
                    else if (part == 2)
                        vb[(((size_t)(b * H_ + h)) * D_ + d) * Q_ + qq] = (bf16)c;
                    else {
                        const int gcol = n & 511;
                        const float x = c + bvec[gcol];
                        gb[(size_t)m * 512 + gcol] = (bf16)(1.f / (1.f + __expf(-x)));
                    }
                } else {
                    fout[(size_t)m * 512 + n] = c + bvec[n];
                }
            }
        }
    }
}

// ---------------------------------------------------------------------------
// MFMA flash attention. Block = 4 waves; 64 queries of one (b,h); wave = 16 rows.
// q/k [B,H,Q,D] bf16 (q pre-scaled), v [B,H,D,Q] bf16. gate gb bf16 [M,512].
// Output ogb bf16 [M,512].
// ---------------------------------------------------------------------------
__global__ __launch_bounds__(256)
void attn_kernel(const bf16* __restrict__ qb, const bf16* __restrict__ kb,
                 const bf16* __restrict__ vb, const float* __restrict__ bias,
                 const bf16* __restrict__ g, bf16* __restrict__ og)
{
    __shared__ __align__(16) bf16 Ks[64 * 80];      // [key][d]   pad 80
    __shared__ __align__(16) bf16 Vs[64 * 80];      // [d][key]   pad 80
    __shared__ __align__(16) bf16 Ps[4][16 * 80];   // per-wave [qrow][key]

    const int tid  = threadIdx.x;
    const int wv   = tid >> 6, lane = tid & 63;
    const int l15  = lane & 15, quad = lane >> 4;
    const int bh   = blockIdx.y;             // b*H + h
    const int b    = bh >> 3, h = bh & 7;
    const int q0   = blockIdx.x * 64;
    const int qrow = q0 + wv * 16;

    const bf16* qptr = qb + ((size_t)bh * Q_ + qrow + l15) * D_;
    const bf16x8 aq0 = *(const bf16x8*)(qptr + quad * 8);
    const bf16x8 aq1 = *(const bf16x8*)(qptr + 32 + quad * 8);

    f32x4 acc_o[4] = {};
    float mrow[4] = {-INFINITY, -INFINITY, -INFINITY, -INFINITY};
    float lrow[4] = {0.f, 0.f, 0.f, 0.f};

    const bf16*  kbase = kb + (size_t)bh * Q_ * D_;
    const bf16*  vbase = vb + (size_t)bh * D_ * Q_;
    const float* brow  = bias + (size_t)b * Q_ * Q_;

    for (int k0 = 0; k0 < Q_; k0 += 64) {
        __syncthreads();
        #pragma unroll
        for (int p = 0; p < 2; ++p) {
            const int elem = p * 2048 + tid * 8;
            const int rr = elem >> 6, cc = elem & 63;
            *(float4*)(Ks + rr * 80 + cc) =
                *(const float4*)(kbase + (size_t)k0 * 64 + elem);
            *(float4*)(Vs + rr * 80 + cc) =
                *(const float4*)(vbase + (size_t)rr * Q_ + k0 + cc);
        }
        __syncthreads();

        float sc[4][4];
        #pragma unroll
        for (int kt = 0; kt < 4; ++kt) {
            f32x4 sacc = {0.f, 0.f, 0.f, 0.f};
            const bf16* kp = Ks + (kt * 16 + l15) * 80 + quad * 8;
            const bf16x8 bk0 = *(const bf16x8*)(kp);
            const bf16x8 bk1 = *(const bf16x8*)(kp + 32);
            sacc = __builtin_amdgcn_mfma_f32_16x16x32_bf16(aq0, bk0, sacc, 0, 0, 0);
            sacc = __builtin_amdgcn_mfma_f32_16x16x32_bf16(aq1, bk1, sacc, 0, 0, 0);
            const float* bp = brow + (size_t)(qrow + quad * 4) * Q_ + k0 + kt * 16 + l15;
            #pragma unroll
            for (int r = 0; r < 4; ++r) sc[kt][r] = sacc[r] + bp[(size_t)r * Q_];
        }

        float tmax[4];
        #pragma unroll
        for (int r = 0; r < 4; ++r)
            tmax[r] = fmaxf(fmaxf(sc[0][r], sc[1][r]), fmaxf(sc[2][r], sc[3][r]));
        #pragma unroll
        for (int off = 1; off < 16; off <<= 1)
            #pragma unroll
            for (int r = 0; r < 4; ++r)
                tmax[r] = fmaxf(tmax[r], __shfl_xor(tmax[r], off, 64));

        float alpha[4];
        #pragma unroll
        for (int r = 0; r < 4; ++r) {
            const float mn = fmaxf(mrow[r], tmax[r]);
            alpha[r] = __expf(mrow[r] - mn);
            mrow[r] = mn;
        }
        float rsum[4];
        #pragma unroll
        for (int r = 0; r < 4; ++r) {
            #pragma unroll
            for (int kt = 0; kt < 4; ++kt) sc[kt][r] = __expf(sc[kt][r] - mrow[r]);
            rsum[r] = sc[0][r] + sc[1][r] + sc[2][r] + sc[3][r];
        }
        #pragma unroll
        for (int off = 1; off < 16; off <<= 1)
            #pragma unroll
            for (int r = 0; r < 4; ++r)
                rsum[r] += __shfl_xor(rsum[r], off, 64);
        #pragma unroll
        for (int r = 0; r < 4; ++r) lrow[r] = lrow[r] * alpha[r] + rsum[r];
        #pragma unroll
        for (int dt = 0; dt < 4; ++dt)
            #pragma unroll
            for (int r = 0; r < 4; ++r) acc_o[dt][r] *= alpha[r];

        bf16* pw = Ps[wv];
        #pragma unroll
        for (int kt = 0; kt < 4; ++kt)
            #pragma unroll
            for (int r = 0; r < 4; ++r)
                pw[(quad * 4 + r) * 80 + kt * 16 + l15] = (bf16)sc[kt][r];
        __asm__ volatile("s_waitcnt lgkmcnt(0)" ::: "memory");

        #pragma unroll
        for (int kt2 = 0; kt2 < 2; ++kt2) {
            const bf16x8 ap = *(const bf16x8*)(pw + l15 * 80 + kt2 * 32 + quad * 8);
            #pragma unroll
            for (int dt = 0; dt < 4; ++dt) {
                const bf16x8 bv = *(const bf16x8*)(Vs + (dt * 16 + l15) * 80 + kt2 * 32 + quad * 8);
                acc_o[dt] = __builtin_amdgcn_mfma_f32_16x16x32_bf16(ap, bv, acc_o[dt], 0, 0, 0);
            }
        }
    }

    #pragma unroll
    for (int r = 0; r < 4; ++r) {
        const float inv = 1.f / lrow[r];
        const int qg = qrow + quad * 4 + r;
        const size_t rowoff = ((size_t)(b * Q_ + qg)) * 512 + h * 64;
        #pragma unroll
        for (int dt = 0; dt < 4; ++dt) {
            const int col = dt * 16 + l15;
            og[rowoff + col] = (bf16)(acc_o[dt][r] * inv * (float)g[rowoff + col]);
        }
    }
}

// ---------------------------------------------------------------------------
extern "C" void kernel_launch(void* const* d_in, const int* in_sizes, int n_in,
                              void* d_out, int out_size, void* d_ws, size_t ws_size,
                              hipStream_t stream)
{
    const float* q_x   = (const float*)d_in[0];
    const float* bias  = (const float*)d_in[2];
    const float* w_qkv = (const float*)d_in[3];
    const float* w_o   = (const float*)d_in[4];
    const float* b_o   = (const float*)d_in[5];
    const float* w_g   = (const float*)d_in[6];
    const float* b_g   = (const float*)d_in[7];
    float* out = (float*)d_out;

    char* ws = (char*)d_ws;
    bf16* qxb  = (bf16*)(ws);                    // 4 MB   [4096,512]
    bf16* wcat = (bf16*)(ws + (4u  << 20));      // 2 MB   [2048,512] = w_qkv ++ w_g
    bf16* wob  = (bf16*)(ws + (6u  << 20));      // 0.5 MB [512,512]
    bf16* qb   = (bf16*)(ws + (8u  << 20));      // 4 MB   [B,H,Q,D]
    bf16* kb   = (bf16*)(ws + (12u << 20));      // 4 MB   [B,H,Q,D]
    bf16* vb   = (bf16*)(ws + (16u << 20));      // 4 MB   [B,H,D,Q]
    bf16* gb   = (bf16*)(ws + (20u << 20));      // 4 MB   [4096,512]
    bf16* ogb  = (bf16*)(ws + (24u << 20));      // 4 MB   [4096,512]

    // 1) fp32 -> bf16 conversions
    convert_kernel<<<(S0 + S1 + S2 + S3) / (256 * 8), 256, 0, stream>>>(
        q_x, w_qkv, w_g, w_o, qxb, wcat, wob);
    // 2) fused QKV + gate projection (bf16 MFMA), N = 2048
    gemm_bf16<128, 128, 0><<<dim3(32, 16), 256, 0, stream>>>(
        qxb, wcat, b_g, nullptr, qb, kb, vb, gb);
    // 3) MFMA flash attention + gating
    attn_kernel<<<dim3(Q_ / 64, B_ * H_), 256, 0, stream>>>(qb, kb, vb, bias, gb, ogb);
    // 4) output projection + b_o
    gemm_bf16<64, 128, 1><<<dim3(64, 4), 256, 0, stream>>>(
        ogb, wob, b_o, out, nullptr, nullptr, nullptr, nullptr);
}

// Round 3
// 180.770 us; speedup vs baseline: 1.9305x; 1.1296x over previous
//
#include <hip/hip_runtime.h>
#include <math.h>

#define B_  2
#define Q_  2048
#define CQ_ 512
#define H_  8
#define D_  64
#define M_  (B_*Q_)   // 4096

typedef __bf16 bf16;
typedef __bf16 bf16x4 __attribute__((ext_vector_type(4)));
typedef __bf16 bf16x8 __attribute__((ext_vector_type(8)));
typedef float  f32x4  __attribute__((ext_vector_type(4)));

// async global->LDS, 16 bytes per lane; lds dest = wave-uniform base + lane*16
__device__ __forceinline__ void gl_lds16(const bf16* g, bf16* l) {
    __builtin_amdgcn_global_load_lds(
        (const __attribute__((address_space(1))) unsigned int*)g,
        (__attribute__((address_space(3))) unsigned int*)l, 16, 0, 0);
}

// ---------------------------------------------------------------------------
// fp32 -> bf16 conversion: q_x -> qxb, w_qkv+w_g -> wcat (concat rows), w_o -> wob
// ---------------------------------------------------------------------------
#define S0 (4096*512)    // q_x
#define S1 (1536*512)    // w_qkv
#define S2 (512*512)     // w_g
#define S3 (512*512)     // w_o
__global__ __launch_bounds__(256)
void convert_kernel(const float* __restrict__ qx, const float* __restrict__ wqkv,
                    const float* __restrict__ wg, const float* __restrict__ wo,
                    bf16* __restrict__ qxb, bf16* __restrict__ wcat, bf16* __restrict__ wob)
{
    const long long t = (long long)blockIdx.x * 256 + threadIdx.x;
    const long long e = t * 8;
    const float* src; bf16* dst;
    if (e < S0)                { src = qx + e;                  dst = qxb + e; }
    else if (e < S0 + S1)      { src = wqkv + (e - S0);         dst = wcat + (e - S0); }
    else if (e < S0 + S1 + S2) { src = wg + (e - S0 - S1);      dst = wcat + S1 + (e - S0 - S1); }
    else                       { src = wo + (e - S0 - S1 - S2); dst = wob + (e - S0 - S1 - S2); }
    const float4 a = *(const float4*)(src);
    const float4 b = *(const float4*)(src + 4);
    bf16x8 v;
    v[0] = (bf16)a.x; v[1] = (bf16)a.y; v[2] = (bf16)a.z; v[3] = (bf16)a.w;
    v[4] = (bf16)b.x; v[5] = (bf16)b.y; v[6] = (bf16)b.z; v[7] = (bf16)b.w;
    *(bf16x8*)dst = v;
}

// ---------------------------------------------------------------------------
// bf16 MFMA GEMM: C[M,N] = A[M,512] * W[N,512]^T, K=512, BK=32.
// Block 256 = 4 waves in 2x2; wave tile (BM/2)x(BN/2); 16x16x32 MFMA.
// EPI 0: n<512 -> q (scaled, bf16 [B,H,Q,D]); <1024 -> k; <1536 -> v ([B,H,D,Q]);
//        else gate: sigmoid(c + b_g) -> gb bf16 [M,512]
// EPI 1: out[m*512+n] = c + b_o[n]  (fp32)
// ---------------------------------------------------------------------------
template<int BM, int BN, int EPI>
__global__ __launch_bounds__(256)
void gemm_bf16(const bf16* __restrict__ A, const bf16* __restrict__ W,
               const float* __restrict__ bvec, float* __restrict__ fout,
               bf16* __restrict__ qb, bf16* __restrict__ kb, bf16* __restrict__ vb,
               bf16* __restrict__ gb)
{
    constexpr int MI = BM / 32, NJ = BN / 32;
    __shared__ __align__(16) bf16 As[BM * 32];
    __shared__ __align__(16) bf16 Bs[BN * 32];

    const int t = threadIdx.x;
    const int w = t >> 6, lane = t & 63;
    const int l15 = lane & 15, quad = lane >> 4;
    const int wm = w & 1, wn = w >> 1;
    const int bm = blockIdx.x * BM;
    const int bn = blockIdx.y * BN;

    f32x4 acc[MI][NJ] = {};

    const int rr = t >> 2;              // staging row within 64-row slab
    const int cc = (t & 3) * 8;         // staging k-offset (elements)

    for (int k0 = 0; k0 < 512; k0 += 32) {
        #pragma unroll
        for (int i = 0; i < BM / 64; ++i)
            gl_lds16(A + (size_t)(bm + i * 64 + rr) * 512 + k0 + cc,
                     As + (i * 64 + w * 16) * 32);
        #pragma unroll
        for (int i = 0; i < BN / 64; ++i)
            gl_lds16(W + (size_t)(bn + i * 64 + rr) * 512 + k0 + cc,
                     Bs + (i * 64 + w * 16) * 32);
        __asm__ volatile("s_waitcnt vmcnt(0)" ::: "memory");
        __syncthreads();

        bf16x8 af[MI], bfr[NJ];
        #pragma unroll
        for (int i = 0; i < MI; ++i)
            af[i] = *(const bf16x8*)(As + (wm * (BM / 2) + i * 16 + l15) * 32 + quad * 8);
        #pragma unroll
        for (int j = 0; j < NJ; ++j)
            bfr[j] = *(const bf16x8*)(Bs + (wn * (BN / 2) + j * 16 + l15) * 32 + quad * 8);
        #pragma unroll
        for (int i = 0; i < MI; ++i)
            #pragma unroll
            for (int j = 0; j < NJ; ++j)
                acc[i][j] = __builtin_amdgcn_mfma_f32_16x16x32_bf16(af[i], bfr[j], acc[i][j], 0, 0, 0);
        __syncthreads();
    }

    #pragma unroll
    for (int i = 0; i < MI; ++i) {
        #pragma unroll
        for (int r = 0; r < 4; ++r) {
            const int m = bm + wm * (BM / 2) + i * 16 + quad * 4 + r;
            const int b = m >> 11, qq = m & 2047;
            #pragma unroll
            for (int j = 0; j < NJ; ++j) {
                const int n = bn + wn * (BN / 2) + j * 16 + l15;
                const float c = acc[i][j][r];
                if constexpr (EPI == 0) {
                    const int part = n >> 9;
                    const int h = (n >> 6) & 7, d = n & 63;
                    if (part == 0)
                        qb[(((size_t)(b * H_ + h)) * Q_ + qq) * D_ + d] = (bf16)(c * 0.125f);
                    else if (part == 1)
                        kb[(((size_t)(b * H_ + h)) * Q_ + qq) * D_ + d] = (bf16)c;
                    else if (part == 2)
                        vb[(((size_t)(b * H_ + h)) * D_ + d) * Q_ + qq] = (bf16)c;
                    else {
                        const int gcol = n & 511;
                        const float x = c + bvec[gcol];
                        gb[(size_t)m * 512 + gcol] = (bf16)(1.f / (1.f + __expf(-x)));
                    }
                } else {
                    fout[(size_t)m * 512 + n] = c + bvec[n];
                }
            }
        }
    }
}

// ---------------------------------------------------------------------------
// Transposed-dataflow MFMA flash attention.
// Block = 4 waves; 64 queries of one (b,h); wave = 16 q-rows; key tiles of 64.
// Scores computed as S^T (A=K, B=Q): each lane holds 16 scores of ONE q-row
// (qrow = q0+wv*16+l15), keys kt*16+quad*4+r.  Softmax: 15 local ops + 2
// shuffles.  P stored [qrow][key] via 4x ds_write_b64 (conflict-free).
// PV as O^T = V^T * P^T (A=V^T from LDS [d][key], B=P^T).  Double-buffered
// K/V via register prefetch: ONE barrier per tile.  Pads = 72 (2-way, free).
// ---------------------------------------------------------------------------
__global__ __launch_bounds__(256)
void attn_kernel(const bf16* __restrict__ qb, const bf16* __restrict__ kb,
                 const bf16* __restrict__ vb, const float* __restrict__ bias,
                 const bf16* __restrict__ g, bf16* __restrict__ og)
{
    __shared__ __align__(16) bf16 Ks[2][64 * 72];
    __shared__ __align__(16) bf16 Vs[2][64 * 72];
    __shared__ __align__(16) bf16 Ps[4][16 * 72];

    const int tid  = threadIdx.x;
    const int wv   = tid >> 6, lane = tid & 63;
    const int l15  = lane & 15, quad = lane >> 4;
    const int bh   = blockIdx.x;             // b*H + h  (x-major: heads share bias in L2)
    const int b    = bh >> 3, h = bh & 7;
    const int q0   = blockIdx.y * 64;
    const int qrow = q0 + wv * 16 + l15;     // this lane's query row

    // Q fragment as B-operand: B[k=d][n=qrow-local=l15]
    const bf16* qptr = qb + ((size_t)bh * Q_ + qrow) * D_;
    const bf16x8 bq0 = *(const bf16x8*)(qptr + quad * 8);
    const bf16x8 bq1 = *(const bf16x8*)(qptr + 32 + quad * 8);

    f32x4 acc[4] = {};                       // O^T: acc[dt][r] = O[qrow][dt*16+quad*4+r]
    float m_run = -INFINITY, l_run = 0.f;

    const bf16*  kbase = kb + (size_t)bh * Q_ * D_;
    const bf16*  vbase = vb + (size_t)bh * D_ * Q_;
    const float* brow  = bias + ((size_t)b * Q_ + qrow) * Q_;

    const int sr  = tid >> 3;                // 0..31 staging row
    const int sc8 = (tid & 7) * 8;           // staging col (elements)

    float4 kreg0, kreg1, vreg0, vreg1;
    float4 bias_cur[4], bias_nxt[4];

    // ---- prologue: stage tile 0, load bias tile 0 ----
    kreg0 = *(const float4*)(kbase + (size_t)sr * 64 + sc8);
    kreg1 = *(const float4*)(kbase + (size_t)(32 + sr) * 64 + sc8);
    vreg0 = *(const float4*)(vbase + (size_t)sr * Q_ + sc8);
    vreg1 = *(const float4*)(vbase + (size_t)(32 + sr) * Q_ + sc8);
    #pragma unroll
    for (int kt = 0; kt < 4; ++kt)
        bias_cur[kt] = *(const float4*)(brow + kt * 16 + quad * 4);
    *(float4*)(Ks[0] + sr * 72 + sc8) = kreg0;
    *(float4*)(Ks[0] + (32 + sr) * 72 + sc8) = kreg1;
    *(float4*)(Vs[0] + sr * 72 + sc8) = vreg0;
    *(float4*)(Vs[0] + (32 + sr) * 72 + sc8) = vreg1;
    __syncthreads();

    int cur = 0;
    for (int t = 0; t < 32; ++t) {
        // prefetch next K/V tile + next bias into registers (latency hidden by compute)
        if (t < 31) {
            const int k0n = (t + 1) * 64;
            kreg0 = *(const float4*)(kbase + ((size_t)k0n + sr) * 64 + sc8);
            kreg1 = *(const float4*)(kbase + ((size_t)k0n + 32 + sr) * 64 + sc8);
            vreg0 = *(const float4*)(vbase + (size_t)sr * Q_ + k0n + sc8);
            vreg1 = *(const float4*)(vbase + (size_t)(32 + sr) * Q_ + k0n + sc8);
            #pragma unroll
            for (int kt = 0; kt < 4; ++kt)
                bias_nxt[kt] = *(const float4*)(brow + k0n + kt * 16 + quad * 4);
        }

        const bf16* Kc = Ks[cur];
        const bf16* Vc = Vs[cur];

        // ---- scores S^T: C[m=key-local][n=qrow-local] ----
        float sc[4][4];                      // [kt][r]: key = kt*16+quad*4+r
        #pragma unroll
        for (int kt = 0; kt < 4; ++kt) {
            f32x4 sacc = {0.f, 0.f, 0.f, 0.f};
            const bf16* kp = Kc + (kt * 16 + l15) * 72 + quad * 8;
            const bf16x8 ak0 = *(const bf16x8*)(kp);
            const bf16x8 ak1 = *(const bf16x8*)(kp + 32);
            sacc = __builtin_amdgcn_mfma_f32_16x16x32_bf16(ak0, bq0, sacc, 0, 0, 0);
            sacc = __builtin_amdgcn_mfma_f32_16x16x32_bf16(ak1, bq1, sacc, 0, 0, 0);
            sc[kt][0] = sacc[0] + bias_cur[kt].x;
            sc[kt][1] = sacc[1] + bias_cur[kt].y;
            sc[kt][2] = sacc[2] + bias_cur[kt].z;
            sc[kt][3] = sacc[3] + bias_cur[kt].w;
        }

        // ---- online softmax: per-lane row, 2 shuffles per reduction ----
        float tmax = -INFINITY;
        #pragma unroll
        for (int kt = 0; kt < 4; ++kt)
            tmax = fmaxf(tmax, fmaxf(fmaxf(sc[kt][0], sc[kt][1]),
                                     fmaxf(sc[kt][2], sc[kt][3])));
        tmax = fmaxf(tmax, __shfl_xor(tmax, 16, 64));
        tmax = fmaxf(tmax, __shfl_xor(tmax, 32, 64));

        const float mn = fmaxf(m_run, tmax);
        const float alpha = __expf(m_run - mn);   // exp(-inf)=0 on first tile
        m_run = mn;

        float rsum = 0.f;
        #pragma unroll
        for (int kt = 0; kt < 4; ++kt)
            #pragma unroll
            for (int r = 0; r < 4; ++r) {
                sc[kt][r] = __expf(sc[kt][r] - mn);
                rsum += sc[kt][r];
            }
        rsum += __shfl_xor(rsum, 16, 64);
        rsum += __shfl_xor(rsum, 32, 64);
        l_run = l_run * alpha + rsum;
        #pragma unroll
        for (int dt = 0; dt < 4; ++dt) acc[dt] *= alpha;

        // ---- P^T -> LDS [qrow][key]: 4x packed b64, conflict-free ----
        bf16* pw = Ps[wv] + l15 * 72;
        #pragma unroll
        for (int kt = 0; kt < 4; ++kt) {
            bf16x4 p4;
            p4[0] = (bf16)sc[kt][0]; p4[1] = (bf16)sc[kt][1];
            p4[2] = (bf16)sc[kt][2]; p4[3] = (bf16)sc[kt][3];
            *(bf16x4*)(pw + kt * 16 + quad * 4) = p4;
        }
        __asm__ volatile("s_waitcnt lgkmcnt(0)" ::: "memory");

        // ---- PV: O^T = V^T * P^T ----
        #pragma unroll
        for (int kt2 = 0; kt2 < 2; ++kt2) {
            const bf16x8 bp = *(const bf16x8*)(pw + kt2 * 32 + quad * 8);
            #pragma unroll
            for (int dt = 0; dt < 4; ++dt) {
                const bf16x8 av = *(const bf16x8*)(Vc + (dt * 16 + l15) * 72 + kt2 * 32 + quad * 8);
                acc[dt] = __builtin_amdgcn_mfma_f32_16x16x32_bf16(av, bp, acc[dt], 0, 0, 0);
            }
        }

        // ---- stage prefetched tile into other buffer; one barrier ----
        if (t < 31) {
            *(float4*)(Ks[cur ^ 1] + sr * 72 + sc8) = kreg0;
            *(float4*)(Ks[cur ^ 1] + (32 + sr) * 72 + sc8) = kreg1;
            *(float4*)(Vs[cur ^ 1] + sr * 72 + sc8) = vreg0;
            *(float4*)(Vs[cur ^ 1] + (32 + sr) * 72 + sc8) = vreg1;
            #pragma unroll
            for (int kt = 0; kt < 4; ++kt) bias_cur[kt] = bias_nxt[kt];
        }
        __syncthreads();
        cur ^= 1;
    }

    // ---- normalize, gate, store bf16 ----
    const float inv = 1.f / l_run;
    const size_t obase = ((size_t)(b * Q_ + qrow)) * 512 + h * 64;
    #pragma unroll
    for (int dt = 0; dt < 4; ++dt) {
        const bf16x4 gv = *(const bf16x4*)(g + obase + dt * 16 + quad * 4);
        bf16x4 ov;
        #pragma unroll
        for (int r = 0; r < 4; ++r)
            ov[r] = (bf16)(acc[dt][r] * inv * (float)gv[r]);
        *(bf16x4*)(og + obase + dt * 16 + quad * 4) = ov;
    }
}

// ---------------------------------------------------------------------------
extern "C" void kernel_launch(void* const* d_in, const int* in_sizes, int n_in,
                              void* d_out, int out_size, void* d_ws, size_t ws_size,
                              hipStream_t stream)
{
    const float* q_x   = (const float*)d_in[0];
    const float* bias  = (const float*)d_in[2];
    const float* w_qkv = (const float*)d_in[3];
    const float* w_o   = (const float*)d_in[4];
    const float* b_o   = (const float*)d_in[5];
    const float* w_g   = (const float*)d_in[6];
    const float* b_g   = (const float*)d_in[7];
    float* out = (float*)d_out;

    char* ws = (char*)d_ws;
    bf16* qxb  = (bf16*)(ws);                    // 4 MB   [4096,512]
    bf16* wcat = (bf16*)(ws + (4u  << 20));      // 2 MB   [2048,512] = w_qkv ++ w_g
    bf16* wob  = (bf16*)(ws + (6u  << 20));      // 0.5 MB [512,512]
    bf16* qb   = (bf16*)(ws + (8u  << 20));      // 4 MB   [B,H,Q,D]
    bf16* kb   = (bf16*)(ws + (12u << 20));      // 4 MB   [B,H,Q,D]
    bf16* vb   = (bf16*)(ws + (16u << 20));      // 4 MB   [B,H,D,Q]
    bf16* gb   = (bf16*)(ws + (20u << 20));      // 4 MB   [4096,512]
    bf16* ogb  = (bf16*)(ws + (24u << 20));      // 4 MB   [4096,512]

    // 1) fp32 -> bf16 conversions
    convert_kernel<<<(S0 + S1 + S2 + S3) / (256 * 8), 256, 0, stream>>>(
        q_x, w_qkv, w_g, w_o, qxb, wcat, wob);
    // 2) fused QKV + gate projection (bf16 MFMA), N = 2048
    gemm_bf16<128, 128, 0><<<dim3(32, 16), 256, 0, stream>>>(
        qxb, wcat, b_g, nullptr, qb, kb, vb, gb);
    // 3) MFMA flash attention + gating (x = bh for bias L2 locality)
    attn_kernel<<<dim3(B_ * H_, Q_ / 64), 256, 0, stream>>>(qb, kb, vb, bias, gb, ogb);
    // 4) output projection + b_o
    gemm_bf16<64, 128, 1><<<dim3(64, 4), 256, 0, stream>>>(
        ogb, wob, b_o, out, nullptr, nullptr, nullptr, nullptr);
}